// Round 1
// baseline (1433.460 us; speedup 1.0000x reference)
//
#include <hip/hip_runtime.h>

constexpr int F_IN  = 256;
constexpr int F_OUT = 128;

constexpr int BSHIFT = 6;
constexpr int BUCKET = 1 << BSHIFT;      // 64 dst nodes per bucket
constexpr int NSHARD = 8;                // append shards per bucket
constexpr int SCAP   = 256;              // per-shard capacity (Poisson(128), 11 sigma headroom)
constexpr int CAP    = NSHARD * SCAP;    // 2048 slots per bucket

typedef __attribute__((ext_vector_type(8))) short short8;
typedef __attribute__((ext_vector_type(4))) float f32x4;

// fp32 -> bf16 round-to-nearest-even
__device__ __forceinline__ unsigned short f2bf(float f) {
    unsigned u = __float_as_uint(f);
    u += 0x7fffu + ((u >> 16) & 1u);
    return (unsigned short)(u >> 16);
}

// ---------------------------------------------------------------------------
// Prep: Wt swizzled K-major: Wt[(ks*128 + n)*32 + kk] = bf16(W[k][n]),
// k = ks*32+kk. Staging step ks then reads one contiguous 8KB block.
// ---------------------------------------------------------------------------
__global__ void prep_wt_kernel(const float* __restrict__ W,
                               unsigned short* __restrict__ Wt)
{
    int n = blockIdx.x;      // 0..127
    int k = threadIdx.x;     // 0..255
    int ks = k >> 5, kk = k & 31;
    Wt[((ks * F_OUT) + n) * 32 + kk] = f2bf(W[k * F_OUT + n]);
}

// ---------------------------------------------------------------------------
// Stage 1: h = bf16(x @ W) via MFMA 16x16x32 bf16. (unchanged)
// ---------------------------------------------------------------------------
#define BS_LD 40   // 32 + 8 pad shorts; 80B row stride, 16B aligned

__global__ __launch_bounds__(256) void gemm_mfma_kernel(
    const float* __restrict__ x, const unsigned short* __restrict__ Wt,
    unsigned short* __restrict__ h, int n_nodes)
{
    __shared__ unsigned short Bs[F_OUT * BS_LD];   // 10240 B

    const int tid  = threadIdx.x;
    const int wave = tid >> 6;
    const int lane = tid & 63;
    const int m16  = lane & 15;
    const int quad = lane >> 4;          // 0..3
    const int k0q  = quad * 8;
    const int arow = blockIdx.x * 64 + wave * 16 + m16;
    const bool inb = arow < n_nodes;

    f32x4 acc[8];
    #pragma unroll
    for (int t = 0; t < 8; ++t) acc[t] = (f32x4)(0.f);

    float4 a0 = make_float4(0.f,0.f,0.f,0.f), a1 = a0;
    if (inb) {
        a0 = *(const float4*)&x[(long long)arow * F_IN + k0q];
        a1 = *(const float4*)&x[(long long)arow * F_IN + k0q + 4];
    }

    for (int ks = 0; ks < 8; ++ks) {
        const uint4* wsrc = (const uint4*)(Wt + (size_t)ks * F_OUT * 32);
        #pragma unroll
        for (int p = 0; p < 2; ++p) {
            int c   = p * 256 + tid;        // 0..511
            int row = c >> 2;               // 0..127
            int o16 = c & 3;                // 0..3
            *(uint4*)&Bs[row * BS_LD + o16 * 8] = wsrc[c];
        }
        __syncthreads();

        short8 af;
        af[0] = (short)f2bf(a0.x); af[1] = (short)f2bf(a0.y);
        af[2] = (short)f2bf(a0.z); af[3] = (short)f2bf(a0.w);
        af[4] = (short)f2bf(a1.x); af[5] = (short)f2bf(a1.y);
        af[6] = (short)f2bf(a1.z); af[7] = (short)f2bf(a1.w);
        if (!inb) af = (short8)0;

        if (ks < 7 && inb) {
            int kn = (ks + 1) * 32 + k0q;
            a0 = *(const float4*)&x[(long long)arow * F_IN + kn];
            a1 = *(const float4*)&x[(long long)arow * F_IN + kn + 4];
        }

        #pragma unroll
        for (int t = 0; t < 8; ++t) {
            int n = t * 16 + m16;
            short8 bf = *(const short8*)&Bs[n * BS_LD + k0q];
            acc[t] = __builtin_amdgcn_mfma_f32_16x16x32_bf16(af, bf, acc[t], 0, 0, 0);
        }
        __syncthreads();
    }

    const int rbase = blockIdx.x * 64 + wave * 16 + quad * 4;
    #pragma unroll
    for (int r = 0; r < 4; ++r) {
        int grow = rbase + r;
        if (grow < n_nodes) {
            #pragma unroll
            for (int t = 0; t < 8; ++t)
                h[(long long)grow * F_OUT + t * 16 + m16] = f2bf(acc[t][r]);
        }
    }
}

// ---------------------------------------------------------------------------
// Single-pass bucketing: atomic-append into fixed-capacity (bucket,shard)
// segments. Replaces count + scan + ordered append. Shard-major counters
// (cnt[s*nb+b]) keep shards in separate cache lines.
// ---------------------------------------------------------------------------
__global__ __launch_bounds__(256) void append_kernel(
    const int* __restrict__ src, const int* __restrict__ dst,
    const float* __restrict__ vals, int* __restrict__ cnt,
    uint2* __restrict__ payload, int n_edges, int nb)
{
    int i = blockIdx.x * 256 + threadIdx.x;
    if (i >= n_edges) return;
    int d = dst[i];
    int b = d >> BSHIFT;
    int s = blockIdx.x & (NSHARD - 1);
    int pos = atomicAdd(&cnt[s * nb + b], 1);
    if (pos < SCAP)
        payload[((size_t)b << 11) + (s << 8) + pos] =
            make_uint2((unsigned)src[i] | ((unsigned)(d & (BUCKET - 1)) << 24),
                       __float_as_uint(vals[i]));
}

// ---------------------------------------------------------------------------
// Fused aggregate: one block per bucket, 64x128 fp32 accumulator tile in LDS.
// Edge-parallel (no per-node serial chain): each wave streams 2 shard
// segments, unroll 4 -> 4 independent h-row loads in flight per wave.
// Accumulator is column-swizzled: lane l's feature pair (2l, 2l+1) lives at
// columns (l, l+64) -> ds_add_f32 hits bank l&31, 2 lanes/bank = conflict-free.
// Epilogue un-swizzles, adds bias, writes coalesced float4.
// ---------------------------------------------------------------------------
__global__ __launch_bounds__(256) void aggregate_kernel(
    const unsigned short* __restrict__ h, const int* __restrict__ cnt,
    const uint2* __restrict__ payload, const float* __restrict__ bias,
    float* __restrict__ out, int n_nodes, int nb)
{
    __shared__ __align__(16) float acc[BUCKET * F_OUT];   // 32 KiB -> 5 blocks/CU

    const int b    = blockIdx.x;
    const int tid  = threadIdx.x;
    const int wv   = tid >> 6;
    const int lane = tid & 63;
    const unsigned foff = 2u * lane;      // short offset within an h row

    #pragma unroll
    for (int i = tid; i < BUCKET * F_OUT / 4; i += 256)
        ((f32x4*)acc)[i] = (f32x4)(0.f);
    __syncthreads();

    #pragma unroll
    for (int s2 = 0; s2 < 2; ++s2) {
        const int s = wv * 2 + s2;
        int c = cnt[s * nb + b];
        if (c > SCAP) c = SCAP;
        const uint2* seg = payload + ((size_t)b << 11) + (s << 8);

        int e = 0;
        for (; e + 4 <= c; e += 4) {
            uint2 p0 = seg[e], p1 = seg[e + 1], p2 = seg[e + 2], p3 = seg[e + 3];
            unsigned x0 = __builtin_amdgcn_readfirstlane(p0.x);
            unsigned x1 = __builtin_amdgcn_readfirstlane(p1.x);
            unsigned x2 = __builtin_amdgcn_readfirstlane(p2.x);
            unsigned x3 = __builtin_amdgcn_readfirstlane(p3.x);
            unsigned u0 = *(const unsigned*)(h + (((size_t)(x0 & 0xFFFFFFu)) << 7) + foff);
            unsigned u1 = *(const unsigned*)(h + (((size_t)(x1 & 0xFFFFFFu)) << 7) + foff);
            unsigned u2 = *(const unsigned*)(h + (((size_t)(x2 & 0xFFFFFFu)) << 7) + foff);
            unsigned u3 = *(const unsigned*)(h + (((size_t)(x3 & 0xFFFFFFu)) << 7) + foff);
            float v0 = __uint_as_float(__builtin_amdgcn_readfirstlane(p0.y));
            float v1 = __uint_as_float(__builtin_amdgcn_readfirstlane(p1.y));
            float v2 = __uint_as_float(__builtin_amdgcn_readfirstlane(p2.y));
            float v3 = __uint_as_float(__builtin_amdgcn_readfirstlane(p3.y));
            float* a0 = &acc[((x0 >> 24) << 7) + lane];
            float* a1 = &acc[((x1 >> 24) << 7) + lane];
            float* a2 = &acc[((x2 >> 24) << 7) + lane];
            float* a3 = &acc[((x3 >> 24) << 7) + lane];
            atomicAdd(a0,      v0 * __uint_as_float(u0 << 16));
            atomicAdd(a0 + 64, v0 * __uint_as_float(u0 & 0xffff0000u));
            atomicAdd(a1,      v1 * __uint_as_float(u1 << 16));
            atomicAdd(a1 + 64, v1 * __uint_as_float(u1 & 0xffff0000u));
            atomicAdd(a2,      v2 * __uint_as_float(u2 << 16));
            atomicAdd(a2 + 64, v2 * __uint_as_float(u2 & 0xffff0000u));
            atomicAdd(a3,      v3 * __uint_as_float(u3 << 16));
            atomicAdd(a3 + 64, v3 * __uint_as_float(u3 & 0xffff0000u));
        }
        for (; e < c; ++e) {
            uint2 p = seg[e];
            unsigned xx = __builtin_amdgcn_readfirstlane(p.x);
            float v = __uint_as_float(__builtin_amdgcn_readfirstlane(p.y));
            unsigned u = *(const unsigned*)(h + (((size_t)(xx & 0xFFFFFFu)) << 7) + foff);
            float* a = &acc[((xx >> 24) << 7) + lane];
            atomicAdd(a,      v * __uint_as_float(u << 16));
            atomicAdd(a + 64, v * __uint_as_float(u & 0xffff0000u));
        }
    }
    __syncthreads();

    // Epilogue: un-swizzle (col c<64 holds feature 2c; col 64+c holds 2c+1),
    // add bias, coalesced float4 stores. 2048 float4s / 256 threads = 8 iters.
    const int node0 = b << BSHIFT;
    #pragma unroll
    for (int i = tid; i < BUCKET * 32; i += 256) {
        int nd = i >> 5;          // 0..63
        int j  = i & 31;          // float4 index -> features 4j..4j+3
        int g  = node0 + nd;
        if (g < n_nodes) {
            float2 lo = *(const float2*)&acc[(nd << 7) + 2 * j];        // f 4j, 4j+2
            float2 hi = *(const float2*)&acc[(nd << 7) + 64 + 2 * j];   // f 4j+1, 4j+3
            float4 bs = *(const float4*)&bias[4 * j];
            *(float4*)&out[(size_t)g * F_OUT + 4 * j] =
                make_float4(lo.x + bs.x, hi.x + bs.y, lo.y + bs.z, hi.y + bs.w);
        }
    }
}

// ---------------------------------------------------------------------------
extern "C" void kernel_launch(void* const* d_in, const int* in_sizes, int n_in,
                              void* d_out, int out_size, void* d_ws, size_t ws_size,
                              hipStream_t stream)
{
    const float* x     = (const float*)d_in[0];
    const int*   esrc  = (const int*)d_in[1];
    const int*   edst  = (const int*)d_in[2];
    const float* evals = (const float*)d_in[3];
    const float* W     = (const float*)d_in[4];
    const float* bias  = (const float*)d_in[5];
    float*       out   = (float*)d_out;

    const int n_nodes = in_sizes[0] / F_IN;
    const int n_edges = in_sizes[1];
    const int nb      = (n_nodes + BUCKET - 1) >> BSHIFT;   // 1563

    auto align16 = [](size_t v) { return (v + 15) & ~(size_t)15; };
    char*  base = (char*)d_ws;
    size_t off  = 0;
    unsigned short* h  = (unsigned short*)(base + off); off = align16(off + (size_t)n_nodes * F_OUT * 2);
    unsigned short* Wt = (unsigned short*)(base + off); off = align16(off + (size_t)F_IN * F_OUT * 2);
    int*   cnt     = (int*)(base + off);   off = align16(off + (size_t)NSHARD * nb * 4);
    uint2* payload = (uint2*)(base + off); off = align16(off + (size_t)nb * CAP * 8);
    (void)ws_size;

    // 1) dense transform
    prep_wt_kernel<<<F_OUT, F_IN, 0, stream>>>(W, Wt);
    gemm_mfma_kernel<<<(n_nodes + 63) / 64, 256, 0, stream>>>(x, Wt, h, n_nodes);

    // 2) single-pass bucketing (atomic append, fixed-capacity segments)
    hipMemsetAsync(cnt, 0, (size_t)NSHARD * nb * 4, stream);
    append_kernel<<<(n_edges + 255) / 256, 256, 0, stream>>>(
        esrc, edst, evals, cnt, payload, n_edges, nb);

    // 3) fused edge-parallel aggregate into LDS tiles, bias fused
    aggregate_kernel<<<nb, 256, 0, stream>>>(
        h, cnt, payload, bias, out, n_nodes, nb);
}

// Round 2
// 468.556 us; speedup vs baseline: 3.0593x; 3.0593x over previous
//
#include <hip/hip_runtime.h>

constexpr int F_IN  = 256;
constexpr int F_OUT = 128;

constexpr int BSHIFT = 6;
constexpr int BUCKET = 1 << BSHIFT;      // 64 dst nodes per bucket
constexpr int NSHARD = 8;                // cursor shards (~per-XCD)

typedef __attribute__((ext_vector_type(8))) short short8;
typedef __attribute__((ext_vector_type(4))) float f32x4;

// fp32 -> bf16 round-to-nearest-even
__device__ __forceinline__ unsigned short f2bf(float f) {
    unsigned u = __float_as_uint(f);
    u += 0x7fffu + ((u >> 16) & 1u);
    return (unsigned short)(u >> 16);
}

// ---------------------------------------------------------------------------
// Prep: Wt swizzled K-major: Wt[(ks*128 + n)*32 + kk] = bf16(W[k][n]),
// k = ks*32+kk. Staging step ks then reads one contiguous 8KB block.
// ---------------------------------------------------------------------------
__global__ void prep_wt_kernel(const float* __restrict__ W,
                               unsigned short* __restrict__ Wt)
{
    int n = blockIdx.x;      // 0..127
    int k = threadIdx.x;     // 0..255
    int ks = k >> 5, kk = k & 31;
    Wt[((ks * F_OUT) + n) * 32 + kk] = f2bf(W[k * F_OUT + n]);
}

// ---------------------------------------------------------------------------
// Stage 1: h = bf16(x @ W) via MFMA 16x16x32 bf16.
// Per-K-step LDS staging (8KB slice, row stride 40 shorts -> 2-way bank
// alias only), x prefetched across the barrier. 10KB LDS -> high occupancy.
// ---------------------------------------------------------------------------
#define BS_LD 40   // 32 + 8 pad shorts; 80B row stride, 16B aligned

__global__ __launch_bounds__(256) void gemm_mfma_kernel(
    const float* __restrict__ x, const unsigned short* __restrict__ Wt,
    unsigned short* __restrict__ h, int n_nodes)
{
    __shared__ unsigned short Bs[F_OUT * BS_LD];   // 128*40*2 = 10240 B

    const int tid  = threadIdx.x;
    const int wave = tid >> 6;
    const int lane = tid & 63;
    const int m16  = lane & 15;
    const int quad = lane >> 4;          // 0..3
    const int k0q  = quad * 8;
    const int arow = blockIdx.x * 64 + wave * 16 + m16;
    const bool inb = arow < n_nodes;

    f32x4 acc[8];
    #pragma unroll
    for (int t = 0; t < 8; ++t) acc[t] = (f32x4)(0.f);

    float4 a0 = make_float4(0.f,0.f,0.f,0.f), a1 = a0;
    if (inb) {
        a0 = *(const float4*)&x[(long long)arow * F_IN + k0q];
        a1 = *(const float4*)&x[(long long)arow * F_IN + k0q + 4];
    }

    for (int ks = 0; ks < 8; ++ks) {
        // stage 8KB slice: 512 uint4 chunks, 2 per thread
        const uint4* wsrc = (const uint4*)(Wt + (size_t)ks * F_OUT * 32);
        #pragma unroll
        for (int p = 0; p < 2; ++p) {
            int c   = p * 256 + tid;        // 0..511
            int row = c >> 2;               // 0..127
            int o16 = c & 3;                // 0..3
            *(uint4*)&Bs[row * BS_LD + o16 * 8] = wsrc[c];
        }
        __syncthreads();

        // convert current afrag
        short8 af;
        af[0] = (short)f2bf(a0.x); af[1] = (short)f2bf(a0.y);
        af[2] = (short)f2bf(a0.z); af[3] = (short)f2bf(a0.w);
        af[4] = (short)f2bf(a1.x); af[5] = (short)f2bf(a1.y);
        af[6] = (short)f2bf(a1.z); af[7] = (short)f2bf(a1.w);
        if (!inb) af = (short8)0;

        // prefetch next slice of x
        if (ks < 7 && inb) {
            int kn = (ks + 1) * 32 + k0q;
            a0 = *(const float4*)&x[(long long)arow * F_IN + kn];
            a1 = *(const float4*)&x[(long long)arow * F_IN + kn + 4];
        }

        #pragma unroll
        for (int t = 0; t < 8; ++t) {
            int n = t * 16 + m16;
            short8 bf = *(const short8*)&Bs[n * BS_LD + k0q];
            acc[t] = __builtin_amdgcn_mfma_f32_16x16x32_bf16(af, bf, acc[t], 0, 0, 0);
        }
        __syncthreads();
    }

    // D layout: col = lane&15, row = quad*4 + reg
    const int rbase = blockIdx.x * 64 + wave * 16 + quad * 4;
    #pragma unroll
    for (int r = 0; r < 4; ++r) {
        int grow = rbase + r;
        if (grow < n_nodes) {
            #pragma unroll
            for (int t = 0; t < 8; ++t)
                h[(long long)grow * F_OUT + t * 16 + m16] = f2bf(acc[t][r]);
        }
    }
}

// ---------------------------------------------------------------------------
// Bucket sort (coarse): count -> scan -> append (XCD-sharded cursors)
// ---------------------------------------------------------------------------
__global__ __launch_bounds__(256) void bucket_count_kernel(
    const int* __restrict__ dst, int* __restrict__ cnt, int n_edges)
{
    int i = blockIdx.x * 256 + threadIdx.x;
    if (i < n_edges)
        atomicAdd(&cnt[(dst[i] >> BSHIFT) * NSHARD + (blockIdx.x & (NSHARD - 1))], 1);
}

__global__ __launch_bounds__(1024) void bucket_scan_kernel(
    const int* __restrict__ cnt, int* __restrict__ cursor,
    int* __restrict__ bucket_start, int nb)
{
    __shared__ int s[1024];
    int t = threadIdx.x;
    int b0 = 2 * t, b1 = 2 * t + 1;
    int sum0 = 0, sum1 = 0;
    if (b0 < nb) for (int j = 0; j < NSHARD; ++j) sum0 += cnt[b0 * NSHARD + j];
    if (b1 < nb) for (int j = 0; j < NSHARD; ++j) sum1 += cnt[b1 * NSHARD + j];
    s[t] = sum0 + sum1;
    __syncthreads();
    for (int off = 1; off < 1024; off <<= 1) {
        int tmp = (t >= off) ? s[t - off] : 0;
        __syncthreads();
        s[t] += tmp;
        __syncthreads();
    }
    int run = s[t] - (sum0 + sum1);
    if (b0 < nb) {
        bucket_start[b0] = run;
        for (int j = 0; j < NSHARD; ++j) { cursor[b0 * NSHARD + j] = run; run += cnt[b0 * NSHARD + j]; }
    }
    if (b1 < nb) {
        bucket_start[b1] = run;
        for (int j = 0; j < NSHARD; ++j) { cursor[b1 * NSHARD + j] = run; run += cnt[b1 * NSHARD + j]; }
    }
    if (t == 1023) bucket_start[nb] = s[1023];
}

__global__ __launch_bounds__(256) void bucket_append_kernel(
    const int* __restrict__ src, const int* __restrict__ dst,
    const float* __restrict__ vals, int* __restrict__ cursor,
    uint2* __restrict__ payload, int n_edges)
{
    int i = blockIdx.x * 256 + threadIdx.x;
    if (i >= n_edges) return;
    int d = dst[i];
    int b = d >> BSHIFT;
    int pos = atomicAdd(&cursor[b * NSHARD + (blockIdx.x & (NSHARD - 1))], 1);
    payload[pos] = make_uint2((unsigned)src[i] | ((unsigned)(d & (BUCKET - 1)) << 24),
                              __float_as_uint(vals[i]));
}

// ---------------------------------------------------------------------------
// Local sort: one block per bucket. 64-bin histogram -> scan -> CSR offsets
// -> scatter to sorted[] inside the bucket's contiguous region.
// ---------------------------------------------------------------------------
__global__ __launch_bounds__(256) void local_sort_kernel(
    const uint2* __restrict__ payload, const int* __restrict__ bucket_start,
    uint2* __restrict__ sorted, int* __restrict__ offsets, int n_nodes)
{
    __shared__ int bins[BUCKET];
    __shared__ int bcur[BUCKET];

    const int b   = blockIdx.x;
    const int tid = threadIdx.x;
    const int start = bucket_start[b];
    const int end   = bucket_start[b + 1];

    if (tid < BUCKET) bins[tid] = 0;
    __syncthreads();

    for (int e = start + tid; e < end; e += 256)
        atomicAdd(&bins[payload[e].x >> 24], 1);
    __syncthreads();

    if (tid == 0) {
        int run = start;
        for (int i = 0; i < BUCKET; ++i) { bcur[i] = run; run += bins[i]; }
    }
    __syncthreads();

    if (tid < BUCKET) {
        int node = (b << BSHIFT) + tid;
        if (node < n_nodes) offsets[node] = bcur[tid];
    }
    __syncthreads();   // offsets reads of bcur must complete before scatter mutates it

    for (int e = start + tid; e < end; e += 256) {
        uint2 p = payload[e];
        int pos = atomicAdd(&bcur[p.x >> 24], 1);
        sorted[pos] = p;
    }
}

// ---------------------------------------------------------------------------
// Gather: one wave per dst node, 2 bf16 features per lane, register accum.
// Unroll-16 with clamped indices + zero weights: the common node (deg~16)
// completes in ONE {16 payload loads -> 16 h-row loads} dependency chain,
// i.e. 16 independent 256B loads in flight per wave (vs 2 before).
// Clamped lanes re-read sorted[end-1] / its h row (same cacheline, v=0).
// ---------------------------------------------------------------------------
__global__ __launch_bounds__(256) void gather_kernel(
    const unsigned short* __restrict__ h, const int* __restrict__ offsets,
    const uint2* __restrict__ sv, const float* __restrict__ bias,
    float* __restrict__ out, int n_nodes, int n_edges)
{
    int node = blockIdx.x * 4 + (threadIdx.x >> 6);
    if (node >= n_nodes) return;
    int lane = threadIdx.x & 63;
    int f = lane * 2;

    int start = offsets[node];
    int end   = (node + 1 < n_nodes) ? offsets[node + 1] : n_edges;

    float ax = 0.f, ay = 0.f;

    for (int e = start; e < end; e += 16) {
        uint2 p[16];
        #pragma unroll
        for (int j = 0; j < 16; ++j) {
            int ei = (e + j < end) ? e + j : end - 1;
            p[j] = sv[ei];
        }
        unsigned u[16];
        #pragma unroll
        for (int j = 0; j < 16; ++j)
            u[j] = *(const unsigned*)&h[(size_t)(p[j].x & 0x00FFFFFFu) * F_OUT + f];
        #pragma unroll
        for (int j = 0; j < 16; ++j) {
            float v = (e + j < end) ? __uint_as_float(p[j].y) : 0.f;
            ax += v * __uint_as_float(u[j] << 16);
            ay += v * __uint_as_float(u[j] & 0xffff0000u);
        }
    }

    float2 b = *(const float2*)&bias[f];
    *(float2*)&out[(size_t)node * F_OUT + f] = make_float2(ax + b.x, ay + b.y);
}

// ---------------------------------------------------------------------------
extern "C" void kernel_launch(void* const* d_in, const int* in_sizes, int n_in,
                              void* d_out, int out_size, void* d_ws, size_t ws_size,
                              hipStream_t stream)
{
    const float* x     = (const float*)d_in[0];
    const int*   esrc  = (const int*)d_in[1];
    const int*   edst  = (const int*)d_in[2];
    const float* evals = (const float*)d_in[3];
    const float* W     = (const float*)d_in[4];
    const float* bias  = (const float*)d_in[5];
    float*       out   = (float*)d_out;

    const int n_nodes = in_sizes[0] / F_IN;
    const int n_edges = in_sizes[1];
    const int nb      = (n_nodes + BUCKET - 1) >> BSHIFT;   // 1563

    auto align16 = [](size_t v) { return (v + 15) & ~(size_t)15; };
    char*  base = (char*)d_ws;
    size_t off  = 0;
    unsigned short* h  = (unsigned short*)(base + off); off = align16(off + (size_t)n_nodes * F_OUT * 2);
    unsigned short* Wt = (unsigned short*)(base + off); off = align16(off + (size_t)F_IN * F_OUT * 2);
    int*   cnt          = (int*)(base + off);   off = align16(off + (size_t)nb * NSHARD * 4);
    int*   cursor       = (int*)(base + off);   off = align16(off + (size_t)nb * NSHARD * 4);
    int*   bucket_start = (int*)(base + off);   off = align16(off + (size_t)(nb + 1) * 4);
    int*   offsets      = (int*)(base + off);   off = align16(off + (size_t)n_nodes * 4);
    uint2* payload      = (uint2*)(base + off); off = align16(off + (size_t)n_edges * 8);
    uint2* sorted       = (uint2*)(base + off); off = align16(off + (size_t)n_edges * 8);
    (void)ws_size;

    // 1) dense transform
    prep_wt_kernel<<<F_OUT, F_IN, 0, stream>>>(W, Wt);
    gemm_mfma_kernel<<<(n_nodes + 63) / 64, 256, 0, stream>>>(x, Wt, h, n_nodes);

    // 2) coarse bucket sort by dst>>6, then per-bucket local sort -> CSR
    hipMemsetAsync(cnt, 0, (size_t)nb * NSHARD * 4, stream);
    bucket_count_kernel<<<(n_edges + 255) / 256, 256, 0, stream>>>(edst, cnt, n_edges);
    bucket_scan_kernel<<<1, 1024, 0, stream>>>(cnt, cursor, bucket_start, nb);
    bucket_append_kernel<<<(n_edges + 255) / 256, 256, 0, stream>>>(
        esrc, edst, evals, cursor, payload, n_edges);
    local_sort_kernel<<<nb, 256, 0, stream>>>(
        payload, bucket_start, sorted, offsets, n_nodes);

    // 3) gather (one wave per node, unroll-16 register accumulation), bias fused
    gather_kernel<<<(n_nodes + 3) / 4, 256, 0, stream>>>(
        h, offsets, sorted, bias, out, n_nodes, n_edges);
}

// Round 4
// 358.224 us; speedup vs baseline: 4.0016x; 1.3080x over previous
//
#include <hip/hip_runtime.h>

constexpr int F_IN  = 256;
constexpr int F_OUT = 128;

constexpr int BSHIFT = 6;
constexpr int BUCKET = 1 << BSHIFT;   // 64 dst nodes per fine bucket
constexpr int SUPSH  = 5;             // 32 fine buckets per super-bucket
constexpr int MAXNB  = 2048;          // LDS histogram bound (nb = 1563)
constexpr int EPT    = 16;            // edges/thread in partition passes
constexpr int BATCH  = 256 * EPT;     // 4096 edges per block batch
constexpr int BPS    = 8;             // blocks per super-bucket (pass B)

typedef __attribute__((ext_vector_type(8))) short short8;
typedef __attribute__((ext_vector_type(4))) float f32x4;

// fp32 -> bf16 round-to-nearest-even
__device__ __forceinline__ unsigned short f2bf(float f) {
    unsigned u = __float_as_uint(f);
    u += 0x7fffu + ((u >> 16) & 1u);
    return (unsigned short)(u >> 16);
}

// ---------------------------------------------------------------------------
// Prep: Wt swizzled K-major: Wt[(ks*128 + n)*32 + kk] = bf16(W[k][n]).
// ---------------------------------------------------------------------------
__global__ void prep_wt_kernel(const float* __restrict__ W,
                               unsigned short* __restrict__ Wt)
{
    int n = blockIdx.x;      // 0..127
    int k = threadIdx.x;     // 0..255
    int ks = k >> 5, kk = k & 31;
    Wt[((ks * F_OUT) + n) * 32 + kk] = f2bf(W[k * F_OUT + n]);
}

// ---------------------------------------------------------------------------
// Stage 1: h = bf16(x @ W) via MFMA 16x16x32 bf16. (unchanged, proven)
// ---------------------------------------------------------------------------
#define BS_LD 40   // 32 + 8 pad shorts; 80B row stride, 16B aligned

__global__ __launch_bounds__(256) void gemm_mfma_kernel(
    const float* __restrict__ x, const unsigned short* __restrict__ Wt,
    unsigned short* __restrict__ h, int n_nodes)
{
    __shared__ unsigned short Bs[F_OUT * BS_LD];   // 10240 B

    const int tid  = threadIdx.x;
    const int wave = tid >> 6;
    const int lane = tid & 63;
    const int m16  = lane & 15;
    const int quad = lane >> 4;
    const int k0q  = quad * 8;
    const int arow = blockIdx.x * 64 + wave * 16 + m16;
    const bool inb = arow < n_nodes;

    f32x4 acc[8];
    #pragma unroll
    for (int t = 0; t < 8; ++t) acc[t] = (f32x4)(0.f);

    float4 a0 = make_float4(0.f,0.f,0.f,0.f), a1 = a0;
    if (inb) {
        a0 = *(const float4*)&x[(long long)arow * F_IN + k0q];
        a1 = *(const float4*)&x[(long long)arow * F_IN + k0q + 4];
    }

    for (int ks = 0; ks < 8; ++ks) {
        const uint4* wsrc = (const uint4*)(Wt + (size_t)ks * F_OUT * 32);
        #pragma unroll
        for (int p = 0; p < 2; ++p) {
            int c   = p * 256 + tid;
            int row = c >> 2;
            int o16 = c & 3;
            *(uint4*)&Bs[row * BS_LD + o16 * 8] = wsrc[c];
        }
        __syncthreads();

        short8 af;
        af[0] = (short)f2bf(a0.x); af[1] = (short)f2bf(a0.y);
        af[2] = (short)f2bf(a0.z); af[3] = (short)f2bf(a0.w);
        af[4] = (short)f2bf(a1.x); af[5] = (short)f2bf(a1.y);
        af[6] = (short)f2bf(a1.z); af[7] = (short)f2bf(a1.w);
        if (!inb) af = (short8)0;

        if (ks < 7 && inb) {
            int kn = (ks + 1) * 32 + k0q;
            a0 = *(const float4*)&x[(long long)arow * F_IN + kn];
            a1 = *(const float4*)&x[(long long)arow * F_IN + kn + 4];
        }

        #pragma unroll
        for (int t = 0; t < 8; ++t) {
            int n = t * 16 + m16;
            short8 bf = *(const short8*)&Bs[n * BS_LD + k0q];
            acc[t] = __builtin_amdgcn_mfma_f32_16x16x32_bf16(af, bf, acc[t], 0, 0, 0);
        }
        __syncthreads();
    }

    const int rbase = blockIdx.x * 64 + wave * 16 + quad * 4;
    #pragma unroll
    for (int r = 0; r < 4; ++r) {
        int grow = rbase + r;
        if (grow < n_nodes) {
            #pragma unroll
            for (int t = 0; t < 8; ++t)
                h[(long long)grow * F_OUT + t * 16 + m16] = f2bf(acc[t][r]);
        }
    }
}

// ---------------------------------------------------------------------------
// Histogram of fine-bucket sizes (dst>>6), LDS-aggregated per block.
// ---------------------------------------------------------------------------
__global__ __launch_bounds__(256) void hist_kernel(
    const int* __restrict__ dst, int* __restrict__ cnt, int n_edges, int nb)
{
    __shared__ int hs[MAXNB];
    const int tid = threadIdx.x;
    for (int i = tid; i < nb; i += 256) hs[i] = 0;
    __syncthreads();
    for (int i = blockIdx.x * 256 + tid; i < n_edges; i += gridDim.x * 256)
        atomicAdd(&hs[dst[i] >> BSHIFT], 1);
    __syncthreads();
    for (int i = tid; i < nb; i += 256) {
        int v = hs[i];
        if (v) atomicAdd(&cnt[i], v);
    }
}

// ---------------------------------------------------------------------------
// Scan: exclusive prefix over fine buckets -> bucket_start, cursorB init;
// super-bucket starts -> super_start, cursorA init. One block, nb <= 2047.
// ---------------------------------------------------------------------------
__global__ __launch_bounds__(1024) void scan_kernel(
    const int* __restrict__ cnt, int* __restrict__ bucket_start,
    int* __restrict__ super_start, int* __restrict__ cursorA,
    int* __restrict__ cursorB, int nb, int nsup)
{
    __shared__ int s[1024];
    int t = threadIdx.x;
    int b0 = 2 * t, b1 = 2 * t + 1;
    int c0 = (b0 < nb) ? cnt[b0] : 0;
    int c1 = (b1 < nb) ? cnt[b1] : 0;
    s[t] = c0 + c1;
    __syncthreads();
    for (int off = 1; off < 1024; off <<= 1) {
        int tmp = (t >= off) ? s[t - off] : 0;
        __syncthreads();
        s[t] += tmp;
        __syncthreads();
    }
    int run = s[t] - (c0 + c1);
    if (b0 < nb) { bucket_start[b0] = run; cursorB[b0] = run; }
    run += c0;
    if (b1 < nb) { bucket_start[b1] = run; cursorB[b1] = run; }
    if (t == 1023) bucket_start[nb] = s[1023];
    __syncthreads();
    for (int i = t; i <= nsup; i += 1024) {
        int k = i << SUPSH;
        int v = (k < nb) ? bucket_start[k] : bucket_start[nb];
        super_start[i] = v;
        if (i < nsup) cursorA[i] = v;
    }
}

// ---------------------------------------------------------------------------
// Pass A: 49-way split by super-bucket (dst>>11). LDS-ranked batch scatter:
// per 4096-edge batch, ranks via LDS atomic, ONE global cursor atomic per
// active bin, then writes where each bin gets ~84 consecutive 8B payloads
// (full-line coalesced). Intermediate packing: x = src | (dst&2047)<<17.
// ---------------------------------------------------------------------------
__global__ __launch_bounds__(256) void partition_a_kernel(
    const int* __restrict__ src, const int* __restrict__ dst,
    const float* __restrict__ vals, int* __restrict__ cursorA,
    uint2* __restrict__ payA, int n_edges)
{
    __shared__ int hist[64];
    __shared__ int base[64];
    const int tid = threadIdx.x;
    const int i0  = blockIdx.x * BATCH;

    if (tid < 64) hist[tid] = 0;
    __syncthreads();

    uint2 p[EPT];
    int   sb[EPT];
    int   rk[EPT];
    #pragma unroll
    for (int j = 0; j < EPT; ++j) {
        int i = i0 + j * 256 + tid;
        sb[j] = -1;
        if (i < n_edges) {
            int d = dst[i];
            p[j] = make_uint2((unsigned)src[i] | ((unsigned)(d & 2047) << 17),
                              __float_as_uint(vals[i]));
            sb[j] = d >> (BSHIFT + SUPSH);
            rk[j] = atomicAdd(&hist[sb[j]], 1);
        }
    }
    __syncthreads();
    if (tid < 64) { int v = hist[tid]; if (v) base[tid] = atomicAdd(&cursorA[tid], v); }
    __syncthreads();
    #pragma unroll
    for (int j = 0; j < EPT; ++j)
        if (sb[j] >= 0) payA[base[sb[j]] + rk[j]] = p[j];
}

// ---------------------------------------------------------------------------
// Pass B: within each super-bucket, 32-way split by (dst>>6)&31. Same
// LDS-ranked batch scatter. Emits final payload: src | (dst&63)<<24.
// ---------------------------------------------------------------------------
__global__ __launch_bounds__(256) void partition_b_kernel(
    const uint2* __restrict__ payA, const int* __restrict__ super_start,
    int* __restrict__ cursorB, uint2* __restrict__ payload)
{
    __shared__ int hist[32];
    __shared__ int base[32];
    const int sp  = blockIdx.x / BPS;
    const int sub = blockIdx.x % BPS;
    const int lo  = super_start[sp];
    const int hi  = super_start[sp + 1];
    const int slice = (hi - lo + BPS - 1) / BPS;
    const int start = lo + sub * slice;
    const int end   = min(start + slice, hi);
    const int tid = threadIdx.x;

    for (int b = start; b < end; b += BATCH) {
        if (tid < 32) hist[tid] = 0;
        __syncthreads();
        uint2 p[EPT];
        int   fb[EPT];
        int   rk[EPT];
        #pragma unroll
        for (int j = 0; j < EPT; ++j) {
            int i = b + j * 256 + tid;
            fb[j] = -1;
            if (i < end) {
                p[j] = payA[i];
                fb[j] = (p[j].x >> 23) & 31;      // dst bits [10:6]
                rk[j] = atomicAdd(&hist[fb[j]], 1);
            }
        }
        __syncthreads();
        if (tid < 32) {
            int v = hist[tid];
            if (v) base[tid] = atomicAdd(&cursorB[(sp << SUPSH) + tid], v);
        }
        __syncthreads();
        #pragma unroll
        for (int j = 0; j < EPT; ++j)
            if (fb[j] >= 0) {
                unsigned xf = (p[j].x & 0x1FFFFu) | (((p[j].x >> 17) & 63u) << 24);
                payload[base[fb[j]] + rk[j]] = make_uint2(xf, p[j].y);
            }
        __syncthreads();   // protect hist reuse across batches
    }
}

// ---------------------------------------------------------------------------
// Local sort: one block per bucket. 64-bin histogram -> CSR offsets ->
// scatter within the bucket's contiguous region. (unchanged)
// ---------------------------------------------------------------------------
__global__ __launch_bounds__(256) void local_sort_kernel(
    const uint2* __restrict__ payload, const int* __restrict__ bucket_start,
    uint2* __restrict__ sorted, int* __restrict__ offsets, int n_nodes)
{
    __shared__ int bins[BUCKET];
    __shared__ int bcur[BUCKET];

    const int b   = blockIdx.x;
    const int tid = threadIdx.x;
    const int start = bucket_start[b];
    const int end   = bucket_start[b + 1];

    if (tid < BUCKET) bins[tid] = 0;
    __syncthreads();

    for (int e = start + tid; e < end; e += 256)
        atomicAdd(&bins[payload[e].x >> 24], 1);
    __syncthreads();

    if (tid == 0) {
        int run = start;
        for (int i = 0; i < BUCKET; ++i) { bcur[i] = run; run += bins[i]; }
    }
    __syncthreads();

    if (tid < BUCKET) {
        int node = (b << BSHIFT) + tid;
        if (node < n_nodes) offsets[node] = bcur[tid];
    }
    __syncthreads();

    for (int e = start + tid; e < end; e += 256) {
        uint2 p = payload[e];
        int pos = atomicAdd(&bcur[p.x >> 24], 1);
        sorted[pos] = p;
    }
}

// ---------------------------------------------------------------------------
// Gather: one wave per dst node, unroll-16 batched loads. (unchanged)
// ---------------------------------------------------------------------------
__global__ __launch_bounds__(256) void gather_kernel(
    const unsigned short* __restrict__ h, const int* __restrict__ offsets,
    const uint2* __restrict__ sv, const float* __restrict__ bias,
    float* __restrict__ out, int n_nodes, int n_edges)
{
    int node = blockIdx.x * 4 + (threadIdx.x >> 6);
    if (node >= n_nodes) return;
    int lane = threadIdx.x & 63;
    int f = lane * 2;

    int start = offsets[node];
    int end   = (node + 1 < n_nodes) ? offsets[node + 1] : n_edges;

    float ax = 0.f, ay = 0.f;

    for (int e = start; e < end; e += 16) {
        uint2 p[16];
        #pragma unroll
        for (int j = 0; j < 16; ++j) {
            int ei = (e + j < end) ? e + j : end - 1;
            p[j] = sv[ei];
        }
        unsigned u[16];
        #pragma unroll
        for (int j = 0; j < 16; ++j)
            u[j] = *(const unsigned*)&h[(size_t)(p[j].x & 0x00FFFFFFu) * F_OUT + f];
        #pragma unroll
        for (int j = 0; j < 16; ++j) {
            float v = (e + j < end) ? __uint_as_float(p[j].y) : 0.f;
            ax += v * __uint_as_float(u[j] << 16);
            ay += v * __uint_as_float(u[j] & 0xffff0000u);
        }
    }

    float2 b = *(const float2*)&bias[f];
    *(float2*)&out[(size_t)node * F_OUT + f] = make_float2(ax + b.x, ay + b.y);
}

// ---------------------------------------------------------------------------
extern "C" void kernel_launch(void* const* d_in, const int* in_sizes, int n_in,
                              void* d_out, int out_size, void* d_ws, size_t ws_size,
                              hipStream_t stream)
{
    const float* x     = (const float*)d_in[0];
    const int*   esrc  = (const int*)d_in[1];
    const int*   edst  = (const int*)d_in[2];
    const float* evals = (const float*)d_in[3];
    const float* W     = (const float*)d_in[4];
    const float* bias  = (const float*)d_in[5];
    float*       out   = (float*)d_out;

    const int n_nodes = in_sizes[0] / F_IN;
    const int n_edges = in_sizes[1];
    const int nb      = (n_nodes + BUCKET - 1) >> BSHIFT;          // 1563
    const int nsup    = (nb + (1 << SUPSH) - 1) >> SUPSH;          // 49

    auto align16 = [](size_t v) { return (v + 15) & ~(size_t)15; };
    char*  base = (char*)d_ws;
    size_t off  = 0;
    unsigned short* h  = (unsigned short*)(base + off); off = align16(off + (size_t)n_nodes * F_OUT * 2);
    unsigned short* Wt = (unsigned short*)(base + off); off = align16(off + (size_t)F_IN * F_OUT * 2);
    int*   cnt          = (int*)(base + off);   off = align16(off + (size_t)nb * 4);
    int*   bucket_start = (int*)(base + off);   off = align16(off + (size_t)(nb + 1) * 4);
    int*   super_start  = (int*)(base + off);   off = align16(off + (size_t)(nsup + 1) * 4);
    int*   cursorA      = (int*)(base + off);   off = align16(off + (size_t)nsup * 4);
    int*   cursorB      = (int*)(base + off);   off = align16(off + (size_t)nb * 4);
    int*   offsets      = (int*)(base + off);   off = align16(off + (size_t)n_nodes * 4);
    uint2* payA         = (uint2*)(base + off); off = align16(off + (size_t)n_edges * 8);  // also 'sorted'
    uint2* payload      = (uint2*)(base + off); off = align16(off + (size_t)n_edges * 8);
    uint2* sorted       = payA;   // pass-A buffer is dead after pass B; reuse
    (void)ws_size;

    // 1) dense transform
    prep_wt_kernel<<<F_OUT, F_IN, 0, stream>>>(W, Wt);
    gemm_mfma_kernel<<<(n_nodes + 63) / 64, 256, 0, stream>>>(x, Wt, h, n_nodes);

    // 2) histogram + scan + two-level LDS-ranked partition -> bucket-sorted
    hipMemsetAsync(cnt, 0, (size_t)nb * 4, stream);
    hist_kernel<<<256, 256, 0, stream>>>(edst, cnt, n_edges, nb);
    scan_kernel<<<1, 1024, 0, stream>>>(cnt, bucket_start, super_start,
                                        cursorA, cursorB, nb, nsup);
    partition_a_kernel<<<(n_edges + BATCH - 1) / BATCH, 256, 0, stream>>>(
        esrc, edst, evals, cursorA, payA, n_edges);
    partition_b_kernel<<<nsup * BPS, 256, 0, stream>>>(
        payA, super_start, cursorB, payload);

    // 3) fine CSR within buckets, then gather (bias fused)
    local_sort_kernel<<<nb, 256, 0, stream>>>(
        payload, bucket_start, sorted, offsets, n_nodes);
    gather_kernel<<<(n_nodes + 3) / 4, 256, 0, stream>>>(
        h, offsets, sorted, bias, out, n_nodes, n_edges);
}